// Round 2
// baseline (3747.536 us; speedup 1.0000x reference)
//
#include <hip/hip_runtime.h>
#include <math.h>

// Problem constants (from setup_inputs): N=200000, E=100000, H=100, R=172, T=100
static constexpr int H    = 100;             // hidden
static constexpr int RD   = 172;             // raw msg dim
static constexpr int TDIM = 100;             // time-enc dim
static constexpr int MSGD = 2*H + RD + TDIM; // 472
static constexpr int G3   = 3*H;             // 300

static constexpr int TN   = 16;              // nodes per block in GRU kernel
static constexpr int BLK  = 320;             // 5 waves
static constexpr int MSTR = 476;             // s_msg row stride (mult of 4 floats -> 16B aligned)
static constexpr int MEMS = 104;             // s_mem row stride
static constexpr int GSTR = 404;             // s_g row stride (aliased over s_msg)

__global__ __launch_bounds__(256) void k_init(int* __restrict__ maxt, int* __restrict__ win, int N) {
    int i = blockIdx.x * blockDim.x + threadIdx.x;
    if (i < N) { maxt[i] = (int)0x80000000; win[i] = -1; }
}

__global__ __launch_bounds__(256) void k_maxt(const int* __restrict__ src, const int* __restrict__ dst,
                                              const int* __restrict__ t, int* __restrict__ maxt, int E) {
    int j = blockIdx.x * blockDim.x + threadIdx.x;
    if (j < E) {
        int tj = t[j];
        atomicMax(&maxt[src[j]], tj);
        atomicMax(&maxt[dst[j]], tj);
    }
}

__global__ __launch_bounds__(256) void k_win(const int* __restrict__ src, const int* __restrict__ dst,
                                             const int* __restrict__ t, const int* __restrict__ maxt,
                                             int* __restrict__ win, int E) {
    int j = blockIdx.x * blockDim.x + threadIdx.x;
    if (j < E) {
        int tj = t[j];
        int s = src[j], d = dst[j];
        if (maxt[s] == tj) atomicMax(&win[s], j);        // s-stream message index = j
        if (maxt[d] == tj) atomicMax(&win[d], j + E);    // d-stream message index = j+E
    }
}

__global__ __launch_bounds__(256) void k_lu(const int* __restrict__ last_update, const int* __restrict__ maxt,
                                            float* __restrict__ out_lu, int N) {
    int i = blockIdx.x * blockDim.x + threadIdx.x;
    if (i < N) {
        int m = maxt[i], lu = last_update[i];
        out_lu[i] = (float)(m > lu ? m : lu);  // values <= 1e6, exact in f32
    }
}

__global__ __launch_bounds__(BLK) void k_gru(
    const int* __restrict__ src, const int* __restrict__ dst, const int* __restrict__ t,
    const float* __restrict__ raw_msg, const float* __restrict__ memory,
    const int* __restrict__ last_update, const float* __restrict__ te_w,
    const float* __restrict__ te_b, const float* __restrict__ w_ih,
    const float* __restrict__ w_hh, const float* __restrict__ b_ih,
    const float* __restrict__ b_hh, const int* __restrict__ win,
    float* __restrict__ out_mem, int E, int N)
{
    __shared__ float s_msg[TN * MSTR];   // 16*476*4 = 30464 B (aliased by s_g later)
    __shared__ float s_mem[TN * MEMS];   // 16*104*4 = 6656 B
    __shared__ int   s_other[TN];
    __shared__ int   s_j[TN];
    __shared__ int   s_has[TN];
    __shared__ float s_dt[TN];

    const int tid   = threadIdx.x;
    const int node0 = blockIdx.x * TN;

    // --- meta: decode winning message per node ---
    if (tid < TN) {
        int node = node0 + tid;
        int w    = win[node];
        int has  = (w >= 0);
        int j = 0, other = 0;
        float dt = 0.f;
        if (has) {
            int e = (w < E) ? w : (w - E);
            j     = e;
            other = (w < E) ? dst[e] : src[e];
            dt    = (float)(t[e] - last_update[node]);  // both streams use node's own last_update
        }
        s_j[tid] = j; s_other[tid] = other; s_has[tid] = has; s_dt[tid] = dt;
    }
    __syncthreads();

    // --- stage msg tile + node memory tile into LDS ---
    for (int n = 0; n < TN; ++n) {
        const int node = node0 + n;
        for (int c = tid; c < H; c += BLK) s_mem[n * MEMS + c] = memory[node * H + c];
        if (s_has[n]) {
            const int other = s_other[n];
            const int j     = s_j[n];
            const float dt  = s_dt[n];
            for (int c = tid; c < MSGD; c += BLK) {
                float v;
                if (c < H)             v = memory[node * H + c];
                else if (c < 2*H)      v = memory[other * H + (c - H)];
                else if (c < 2*H+RD)   v = raw_msg[j * RD + (c - 2*H)];
                else { int q = c - (2*H+RD); v = cosf(fmaf(dt, te_w[q], te_b[q])); }
                s_msg[n * MSTR + c] = v;
            }
        } else {
            for (int c = tid; c < MSGD; c += BLK) s_msg[n * MSTR + c] = 0.f;
        }
    }
    __syncthreads();

    // --- per-row GEMV: thread k owns output row k for all TN nodes ---
    float acc_i[TN];
    float acc_h[TN];
    const int k = tid;
    if (k < G3) {
#pragma unroll
        for (int n = 0; n < TN; ++n) { acc_i[n] = 0.f; acc_h[n] = 0.f; }

        const float* wr = w_ih + k * MSGD;
        int c0 = 0;
        for (; c0 + 16 <= MSGD; c0 += 16) {   // 29 iterations (464)
            const float4 wa = *(const float4*)(wr + c0);
            const float4 wb = *(const float4*)(wr + c0 + 4);
            const float4 wc = *(const float4*)(wr + c0 + 8);
            const float4 wd = *(const float4*)(wr + c0 + 12);
#pragma unroll
            for (int n = 0; n < TN; ++n) {
                const float* mrow = &s_msg[n * MSTR + c0];   // wave-uniform -> LDS broadcast
                const float4 ma = *(const float4*)(mrow);
                const float4 mb = *(const float4*)(mrow + 4);
                const float4 mc = *(const float4*)(mrow + 8);
                const float4 md = *(const float4*)(mrow + 12);
                float s = acc_i[n];
                s = fmaf(wa.x, ma.x, s); s = fmaf(wa.y, ma.y, s);
                s = fmaf(wa.z, ma.z, s); s = fmaf(wa.w, ma.w, s);
                s = fmaf(wb.x, mb.x, s); s = fmaf(wb.y, mb.y, s);
                s = fmaf(wb.z, mb.z, s); s = fmaf(wb.w, mb.w, s);
                s = fmaf(wc.x, mc.x, s); s = fmaf(wc.y, mc.y, s);
                s = fmaf(wc.z, mc.z, s); s = fmaf(wc.w, mc.w, s);
                s = fmaf(wd.x, md.x, s); s = fmaf(wd.y, md.y, s);
                s = fmaf(wd.z, md.z, s); s = fmaf(wd.w, md.w, s);
                acc_i[n] = s;
            }
        }
        {   // tail: 8 floats (464..472)
            const float4 wa = *(const float4*)(wr + c0);
            const float4 wb = *(const float4*)(wr + c0 + 4);
#pragma unroll
            for (int n = 0; n < TN; ++n) {
                const float* mrow = &s_msg[n * MSTR + c0];
                const float4 ma = *(const float4*)(mrow);
                const float4 mb = *(const float4*)(mrow + 4);
                float s = acc_i[n];
                s = fmaf(wa.x, ma.x, s); s = fmaf(wa.y, ma.y, s);
                s = fmaf(wa.z, ma.z, s); s = fmaf(wa.w, ma.w, s);
                s = fmaf(wb.x, mb.x, s); s = fmaf(wb.y, mb.y, s);
                s = fmaf(wb.z, mb.z, s); s = fmaf(wb.w, mb.w, s);
                acc_i[n] = s;
            }
        }

        const float* hr = w_hh + k * H;
        int d0 = 0;
        for (; d0 + 16 <= H; d0 += 16) {      // 6 iterations (96)
            const float4 wa = *(const float4*)(hr + d0);
            const float4 wb = *(const float4*)(hr + d0 + 4);
            const float4 wc = *(const float4*)(hr + d0 + 8);
            const float4 wd = *(const float4*)(hr + d0 + 12);
#pragma unroll
            for (int n = 0; n < TN; ++n) {
                const float* mrow = &s_mem[n * MEMS + d0];
                const float4 ma = *(const float4*)(mrow);
                const float4 mb = *(const float4*)(mrow + 4);
                const float4 mc = *(const float4*)(mrow + 8);
                const float4 md = *(const float4*)(mrow + 12);
                float s = acc_h[n];
                s = fmaf(wa.x, ma.x, s); s = fmaf(wa.y, ma.y, s);
                s = fmaf(wa.z, ma.z, s); s = fmaf(wa.w, ma.w, s);
                s = fmaf(wb.x, mb.x, s); s = fmaf(wb.y, mb.y, s);
                s = fmaf(wb.z, mb.z, s); s = fmaf(wb.w, mb.w, s);
                s = fmaf(wc.x, mc.x, s); s = fmaf(wc.y, mc.y, s);
                s = fmaf(wc.z, mc.z, s); s = fmaf(wc.w, mc.w, s);
                s = fmaf(wd.x, md.x, s); s = fmaf(wd.y, md.y, s);
                s = fmaf(wd.w, md.w, s); // keep same op count
                acc_h[n] = s;
            }
        }
        {   // tail: 4 floats (96..100)
            const float4 wa = *(const float4*)(hr + d0);
#pragma unroll
            for (int n = 0; n < TN; ++n) {
                const float4 ma = *(const float4*)(&s_mem[n * MEMS + d0]);
                float s = acc_h[n];
                s = fmaf(wa.x, ma.x, s); s = fmaf(wa.y, ma.y, s);
                s = fmaf(wa.z, ma.z, s); s = fmaf(wa.w, ma.w, s);
                acc_h[n] = s;
            }
        }
    }
    __syncthreads();                // all s_msg reads done; safe to alias

    // --- stage gate pre-activations: [0,2H): gi+gh ; [2H,3H): gi at k, gh at k+H ---
    float* s_g = s_msg;             // alias (16*404 <= 16*476)
    if (k < G3) {
        const float bi = b_ih[k];
        const float bh = b_hh[k];
#pragma unroll
        for (int n = 0; n < TN; ++n) {
            float gi = acc_i[n] + bi;
            float gh = acc_h[n] + bh;
            if (k < 2*H) {
                s_g[n * GSTR + k] = gi + gh;
            } else {
                s_g[n * GSTR + k]     = gi;
                s_g[n * GSTR + k + H] = gh;
            }
        }
    }
    __syncthreads();

    // --- gates + output ---
    for (int item = tid; item < TN * H; item += BLK) {
        const int n   = item / H;
        const int col = item - n * H;
        const float* g = s_g + n * GSTR;
        const float r  = 1.f / (1.f + __expf(-g[col]));
        const float z  = 1.f / (1.f + __expf(-g[col + H]));
        const float nn = tanhf(g[col + 2*H] + r * g[col + 3*H]);
        const float h  = s_mem[n * MEMS + col];
        out_mem[(node0 + n) * H + col] = (1.f - z) * nn + z * h;
    }
}

extern "C" void kernel_launch(void* const* d_in, const int* in_sizes, int n_in,
                              void* d_out, int out_size, void* d_ws, size_t ws_size,
                              hipStream_t stream)
{
    const int*   src         = (const int*)d_in[0];
    const int*   dst         = (const int*)d_in[1];
    const int*   t           = (const int*)d_in[2];
    const float* raw_msg     = (const float*)d_in[3];
    const float* memory      = (const float*)d_in[4];
    const int*   last_update = (const int*)d_in[5];
    const float* te_w        = (const float*)d_in[6];
    const float* te_b        = (const float*)d_in[7];
    const float* w_ih        = (const float*)d_in[8];
    const float* w_hh        = (const float*)d_in[9];
    const float* b_ih        = (const float*)d_in[10];
    const float* b_hh        = (const float*)d_in[11];

    const int E = in_sizes[0];            // 100000
    const int N = in_sizes[5];            // 200000 (last_update size)

    float* out    = (float*)d_out;
    float* out_lu = out + (size_t)N * H;

    int* maxt = (int*)d_ws;
    int* win  = maxt + N;

    k_init<<<(N + 255) / 256, 256, 0, stream>>>(maxt, win, N);
    k_maxt<<<(E + 255) / 256, 256, 0, stream>>>(src, dst, t, maxt, E);
    k_win <<<(E + 255) / 256, 256, 0, stream>>>(src, dst, t, maxt, win, E);
    k_lu  <<<(N + 255) / 256, 256, 0, stream>>>(last_update, maxt, out_lu, N);
    k_gru <<<(N + TN - 1) / TN, BLK, 0, stream>>>(src, dst, t, raw_msg, memory, last_update,
                                                  te_w, te_b, w_ih, w_hh, b_ih, b_hh, win, out, E, N);
}

// Round 3
// 907.779 us; speedup vs baseline: 4.1282x; 4.1282x over previous
//
#include <hip/hip_runtime.h>
#include <math.h>

typedef __attribute__((ext_vector_type(8))) short  short8;
typedef __attribute__((ext_vector_type(4))) float  f32x4;

// Problem constants: N=200000, E=100000, H=100, R=172, T=100
static constexpr int H     = 100;
static constexpr int RD    = 172;
static constexpr int MSGD  = 472;             // 2H + RD + T
static constexpr int KIH   = 480;             // padded ih K (15*32)
static constexpr int KHH   = 128;             // padded hh K (4*32)
static constexpr int KTOT  = 608;             // KIH + KHH
static constexpr int ASTR  = 612;             // sA row stride (ushorts); 612*2B=1224B -> conflict-benign
static constexpr int NT    = 19;              // 16-wide col tiles covering 300 (pad 304)
static constexpr int KS_IH = 15;              // 480/32
static constexpr int KS_HH = 4;               // 128/32
static constexpr int MB    = 32;              // nodes per block
static constexpr int BLK   = 256;             // 4 waves

static constexpr int BIH_N = NT * KS_IH * 64 * 8;   // 145920 ushorts per plane
static constexpr int BHH_N = NT * KS_HH * 64 * 8;   // 38912

__device__ inline unsigned short f2bf(float x) {
    union { float f; unsigned u; } v; v.f = x;
    unsigned u = v.u;
    unsigned r = (u + 0x7FFFu + ((u >> 16) & 1u)) >> 16;
    return (unsigned short)r;
}
__device__ inline float bf2f(unsigned short b) {
    union { unsigned u; float f; } v; v.u = ((unsigned)b) << 16;
    return v.f;
}
__device__ inline f32x4 mfma16(short8 a, short8 b, f32x4 c) {
    return __builtin_amdgcn_mfma_f32_16x16x32_bf16(a, b, c, 0, 0, 0);
}

// ---------------- aggregation kernels ----------------
__global__ __launch_bounds__(256) void k_init(int* __restrict__ maxt, int* __restrict__ win, int N) {
    int i = blockIdx.x * blockDim.x + threadIdx.x;
    if (i < N) { maxt[i] = (int)0x80000000; win[i] = -1; }
}

__global__ __launch_bounds__(256) void k_maxt(const int* __restrict__ src, const int* __restrict__ dst,
                                              const int* __restrict__ t, int* __restrict__ maxt, int E) {
    int j = blockIdx.x * blockDim.x + threadIdx.x;
    if (j < E) {
        int tj = t[j];
        atomicMax(&maxt[src[j]], tj);
        atomicMax(&maxt[dst[j]], tj);
    }
}

__global__ __launch_bounds__(256) void k_win(const int* __restrict__ src, const int* __restrict__ dst,
                                             const int* __restrict__ t, const int* __restrict__ maxt,
                                             int* __restrict__ win, int E) {
    int j = blockIdx.x * blockDim.x + threadIdx.x;
    if (j < E) {
        int tj = t[j];
        int s = src[j], d = dst[j];
        if (maxt[s] == tj) atomicMax(&win[s], j);        // s-stream index j
        if (maxt[d] == tj) atomicMax(&win[d], j + E);    // d-stream index j+E
    }
}

__global__ __launch_bounds__(256) void k_lu(const int* __restrict__ last_update, const int* __restrict__ maxt,
                                            float* __restrict__ out_lu, int N) {
    int i = blockIdx.x * blockDim.x + threadIdx.x;
    if (i < N) {
        int m = maxt[i], lu = last_update[i];
        out_lu[i] = (float)(m > lu ? m : lu);
    }
}

// ---------------- weight prep: bf16 hi/lo, B-fragment packed ----------------
// Pack layout: plane[((tile*KS + ks)*64 + lane)*8 + j] = W[tile*16 + (lane&15)][ks*32 + (lane>>4)*8 + j]
__global__ __launch_bounds__(256) void k_prep(const float* __restrict__ w_ih, const float* __restrict__ w_hh,
                                              unsigned short* __restrict__ bih_hi, unsigned short* __restrict__ bih_lo,
                                              unsigned short* __restrict__ bhh_hi, unsigned short* __restrict__ bhh_lo) {
    int item = blockIdx.x * 256 + threadIdx.x;
    if (item < BIH_N) {
        int j = item & 7, l = (item >> 3) & 63, rest = item >> 9;
        int ks = rest % KS_IH, tile = rest / KS_IH;
        int row = tile * 16 + (l & 15);
        int k   = ks * 32 + ((l >> 4) << 3) + j;
        float v = (row < 300 && k < MSGD) ? w_ih[row * MSGD + k] : 0.f;
        unsigned short hi = f2bf(v);
        bih_hi[item] = hi;
        bih_lo[item] = f2bf(v - bf2f(hi));
    } else if (item < BIH_N + BHH_N) {
        int it2 = item - BIH_N;
        int j = it2 & 7, l = (it2 >> 3) & 63, rest = it2 >> 9;
        int ks = rest % KS_HH, tile = rest / KS_HH;
        int row = tile * 16 + (l & 15);
        int k   = ks * 32 + ((l >> 4) << 3) + j;
        float v = (row < 300 && k < H) ? w_hh[row * H + k] : 0.f;
        unsigned short hi = f2bf(v);
        bhh_hi[it2] = hi;
        bhh_lo[it2] = f2bf(v - bf2f(hi));
    }
}

// ---------------- fused GRU via bf16x3 MFMA ----------------
__global__ __launch_bounds__(BLK) void k_gru(
    const int* __restrict__ src, const int* __restrict__ dst, const int* __restrict__ t,
    const float* __restrict__ raw_msg, const float* __restrict__ memory,
    const int* __restrict__ last_update, const float* __restrict__ te_w,
    const float* __restrict__ te_b, const float* __restrict__ b_ih,
    const float* __restrict__ b_hh, const int* __restrict__ win,
    const unsigned short* __restrict__ bih_hi, const unsigned short* __restrict__ bih_lo,
    const unsigned short* __restrict__ bhh_hi, const unsigned short* __restrict__ bhh_lo,
    float* __restrict__ out_mem, int E, int N)
{
    __shared__ union SM {
        unsigned short a[2][MB * ASTR];                   // [0]=hi, [1]=lo : 78336 B
        struct { float ga[MB * 304]; float gb[MB * 104]; } g; // 52224 B (alias)
    } sm;
    __shared__ int   s_other[MB];
    __shared__ int   s_j[MB];
    __shared__ int   s_has[MB];
    __shared__ float s_dt[MB];

    const int tid   = threadIdx.x;
    const int node0 = blockIdx.x * MB;

    // --- decode winners ---
    if (tid < MB) {
        int node = node0 + tid;
        int w    = win[node];
        int has  = (w >= 0);
        int j = 0, other = 0; float dt = 0.f;
        if (has) {
            int e = (w < E) ? w : (w - E);
            j     = e;
            other = (w < E) ? dst[e] : src[e];
            dt    = (float)(t[e] - last_update[node]);
        }
        s_j[tid] = j; s_other[tid] = other; s_has[tid] = has; s_dt[tid] = dt;
    }
    __syncthreads();

    // --- stage A (msg | mem) as bf16 hi/lo ---
    for (int n = 0; n < MB; ++n) {
        const int node  = node0 + n;
        const int has   = s_has[n];
        const int other = s_other[n];
        const int j     = s_j[n];
        const float dt  = s_dt[n];
        for (int c = tid; c < KTOT; c += BLK) {
            float v = 0.f;
            if (c < MSGD) {
                if (has) {
                    if (c < H)            v = memory[node * H + c];
                    else if (c < 2*H)     v = memory[other * H + (c - H)];
                    else if (c < 2*H+RD)  v = raw_msg[j * RD + (c - 2*H)];
                    else { int q = c - (2*H+RD); v = cosf(fmaf(dt, te_w[q], te_b[q])); }
                }
            } else if (c >= KIH && c < KIH + H) {
                v = memory[node * H + (c - KIH)];
            }
            unsigned short hi = f2bf(v);
            sm.a[0][n * ASTR + c] = hi;
            sm.a[1][n * ASTR + c] = f2bf(v - bf2f(hi));
        }
    }
    __syncthreads();

    // --- MFMA main: D[node][outcol], A=msg rows, B=W^T (pre-packed frags) ---
    const int wid  = tid >> 6;
    const int lane = tid & 63;
    const int lrow = lane & 15;
    const int kc8  = (lane >> 4) << 3;

    f32x4 acc_i[5][2];
    f32x4 acc_h[5][2];
#pragma unroll
    for (int i = 0; i < 5; ++i)
#pragma unroll
        for (int g = 0; g < 2; ++g) { acc_i[i][g] = (f32x4)0.f; acc_h[i][g] = (f32x4)0.f; }

    for (int ks = 0; ks < KS_IH; ++ks) {
        const int ko = ks * 32 + kc8;
        short8 aH0 = *(const short8*)&sm.a[0][(lrow     ) * ASTR + ko];
        short8 aH1 = *(const short8*)&sm.a[0][(16 + lrow) * ASTR + ko];
        short8 aL0 = *(const short8*)&sm.a[1][(lrow     ) * ASTR + ko];
        short8 aL1 = *(const short8*)&sm.a[1][(16 + lrow) * ASTR + ko];
#pragma unroll
        for (int i = 0; i < 5; ++i) {
            const int tl = wid + 4 * i;
            if (tl >= NT) continue;
            const size_t bo = ((size_t)(tl * KS_IH + ks) * 64 + lane) * 8;
            short8 bH = *(const short8*)&bih_hi[bo];
            short8 bL = *(const short8*)&bih_lo[bo];
            acc_i[i][0] = mfma16(aH0, bH, acc_i[i][0]);
            acc_i[i][0] = mfma16(aH0, bL, acc_i[i][0]);
            acc_i[i][0] = mfma16(aL0, bH, acc_i[i][0]);
            acc_i[i][1] = mfma16(aH1, bH, acc_i[i][1]);
            acc_i[i][1] = mfma16(aH1, bL, acc_i[i][1]);
            acc_i[i][1] = mfma16(aL1, bH, acc_i[i][1]);
        }
    }
    for (int ks = 0; ks < KS_HH; ++ks) {
        const int ko = KIH + ks * 32 + kc8;
        short8 aH0 = *(const short8*)&sm.a[0][(lrow     ) * ASTR + ko];
        short8 aH1 = *(const short8*)&sm.a[0][(16 + lrow) * ASTR + ko];
        short8 aL0 = *(const short8*)&sm.a[1][(lrow     ) * ASTR + ko];
        short8 aL1 = *(const short8*)&sm.a[1][(16 + lrow) * ASTR + ko];
#pragma unroll
        for (int i = 0; i < 5; ++i) {
            const int tl = wid + 4 * i;
            if (tl >= NT) continue;
            const size_t bo = ((size_t)(tl * KS_HH + ks) * 64 + lane) * 8;
            short8 bH = *(const short8*)&bhh_hi[bo];
            short8 bL = *(const short8*)&bhh_lo[bo];
            acc_h[i][0] = mfma16(aH0, bH, acc_h[i][0]);
            acc_h[i][0] = mfma16(aH0, bL, acc_h[i][0]);
            acc_h[i][0] = mfma16(aL0, bH, acc_h[i][0]);
            acc_h[i][1] = mfma16(aH1, bH, acc_h[i][1]);
            acc_h[i][1] = mfma16(aH1, bL, acc_h[i][1]);
            acc_h[i][1] = mfma16(aL1, bH, acc_h[i][1]);
        }
    }
    __syncthreads();   // all A reads done; safe to alias g over a

    // --- scatter accumulators to LDS: ga = gi+gh (cols<200) / gi (200..300); gb = gh (200..300) ---
#pragma unroll
    for (int i = 0; i < 5; ++i) {
        const int tl = wid + 4 * i;
        if (tl >= NT) continue;
        const int col = tl * 16 + lrow;
#pragma unroll
        for (int g = 0; g < 2; ++g) {
#pragma unroll
            for (int r = 0; r < 4; ++r) {
                const int noderow = g * 16 + ((lane >> 4) << 2) + r;   // C/D: row=(lane>>4)*4+reg
                const float vi = acc_i[i][g][r];
                const float vh = acc_h[i][g][r];
                if (col < 200) {
                    sm.g.ga[noderow * 304 + col] = vi + vh;
                } else if (col < 300) {
                    sm.g.ga[noderow * 304 + col] = vi;
                    sm.g.gb[noderow * 104 + (col - 200)] = vh;
                }
            }
        }
    }
    __syncthreads();

    // --- gates + output ---
    for (int item = tid; item < MB * H; item += BLK) {
        const int n   = item / H;
        const int col = item - n * H;
        const float* ga = &sm.g.ga[n * 304];
        const float r  = 1.f / (1.f + __expf(-(ga[col]       + b_ih[col]       + b_hh[col])));
        const float z  = 1.f / (1.f + __expf(-(ga[col + 100] + b_ih[col + 100] + b_hh[col + 100])));
        const float hn = sm.g.gb[n * 104 + col] + b_hh[col + 200];
        const float nn = tanhf(ga[col + 200] + b_ih[col + 200] + r * hn);
        const float h  = memory[(node0 + n) * H + col];
        out_mem[(node0 + n) * H + col] = (1.f - z) * nn + z * h;
    }
}

extern "C" void kernel_launch(void* const* d_in, const int* in_sizes, int n_in,
                              void* d_out, int out_size, void* d_ws, size_t ws_size,
                              hipStream_t stream)
{
    const int*   src         = (const int*)d_in[0];
    const int*   dst         = (const int*)d_in[1];
    const int*   t           = (const int*)d_in[2];
    const float* raw_msg     = (const float*)d_in[3];
    const float* memory      = (const float*)d_in[4];
    const int*   last_update = (const int*)d_in[5];
    const float* te_w        = (const float*)d_in[6];
    const float* te_b        = (const float*)d_in[7];
    const float* w_ih        = (const float*)d_in[8];
    const float* w_hh        = (const float*)d_in[9];
    const float* b_ih        = (const float*)d_in[10];
    const float* b_hh        = (const float*)d_in[11];

    const int E = in_sizes[0];   // 100000
    const int N = in_sizes[5];   // 200000

    float* out    = (float*)d_out;
    float* out_lu = out + (size_t)N * H;

    int* maxt = (int*)d_ws;
    int* win  = maxt + N;
    unsigned short* bih_hi = (unsigned short*)(win + N);
    unsigned short* bih_lo = bih_hi + BIH_N;
    unsigned short* bhh_hi = bih_lo + BIH_N;
    unsigned short* bhh_lo = bhh_hi + BHH_N;

    k_init<<<(N + 255) / 256, 256, 0, stream>>>(maxt, win, N);
    k_prep<<<(BIH_N + BHH_N + 255) / 256, 256, 0, stream>>>(w_ih, w_hh, bih_hi, bih_lo, bhh_hi, bhh_lo);
    k_maxt<<<(E + 255) / 256, 256, 0, stream>>>(src, dst, t, maxt, E);
    k_win <<<(E + 255) / 256, 256, 0, stream>>>(src, dst, t, maxt, win, E);
    k_lu  <<<(N + 255) / 256, 256, 0, stream>>>(last_update, maxt, out_lu, N);
    k_gru <<<N / MB, BLK, 0, stream>>>(src, dst, t, raw_msg, memory, last_update,
                                       te_w, te_b, b_ih, b_hh, win,
                                       bih_hi, bih_lo, bhh_hi, bhh_lo, out, E, N);
}

// Round 4
// 346.842 us; speedup vs baseline: 10.8047x; 2.6173x over previous
//
#include <hip/hip_runtime.h>
#include <math.h>

typedef __attribute__((ext_vector_type(8))) short  short8;
typedef __attribute__((ext_vector_type(4))) float  f32x4;

// Problem constants: N=200000, E=100000, H=100, R=172, T=100
static constexpr int H     = 100;
static constexpr int RD    = 172;
static constexpr int WIH_K = 472;            // w_ih col count
// Padded K layout (chunks of 8):
//  [0,104)   mem[node]   (100 + pad)
//  [104,208) mem[other]  (100 + pad)
//  [208,384) raw_msg     (172 + pad)
//  [384,512) time-enc    (100 + pad)
//  [512,640) mem[node]   (hh section, 100 + pad)
static constexpr int KTOT  = 640;
static constexpr int NKS   = 20;             // 640/32 K-steps
static constexpr int KS_IH = 16;             // first 16 steps = ih
static constexpr int NTILE = 21;             // 3 gates x 7 col-tiles (112 cols/gate)
static constexpr int MB    = 48;             // nodes per block
static constexpr int GRPS  = 3;              // MB/16
static constexpr int BLK   = 448;            // 7 waves
static constexpr int NWAVE = 7;
static constexpr int SLOTS = 65;             // per-(grp,ks) tile stride in 16B slots (+1 pad slot)

static constexpr int BPK_N = NTILE * NKS * 64 * 8;   // 215040 bf16 elements

__device__ inline unsigned short f2bf(float x) {
    union { float f; unsigned u; } v; v.f = x;
    unsigned u = v.u;
    return (unsigned short)((u + 0x7FFFu + ((u >> 16) & 1u)) >> 16);
}
__device__ inline f32x4 mfma16(short8 a, short8 b, f32x4 c) {
    return __builtin_amdgcn_mfma_f32_16x16x32_bf16(a, b, c, 0, 0, 0);
}
__device__ inline float4 ld4g(const float* base, int lc, int limit) {
    // limits are multiples of 4 -> never partial
    if (lc + 4 <= limit) return *(const float4*)(base + lc);
    return make_float4(0.f, 0.f, 0.f, 0.f);
}

// ---------------- aggregation kernels ----------------
__global__ __launch_bounds__(256) void k_init(int* __restrict__ maxt, int* __restrict__ win, int N) {
    int i = blockIdx.x * blockDim.x + threadIdx.x;
    if (i < N) { maxt[i] = (int)0x80000000; win[i] = -1; }
}

__global__ __launch_bounds__(256) void k_maxt(const int* __restrict__ src, const int* __restrict__ dst,
                                              const int* __restrict__ t, int* __restrict__ maxt, int E) {
    int j = blockIdx.x * blockDim.x + threadIdx.x;
    if (j < E) {
        int tj = t[j];
        atomicMax(&maxt[src[j]], tj);
        atomicMax(&maxt[dst[j]], tj);
    }
}

__global__ __launch_bounds__(256) void k_win(const int* __restrict__ src, const int* __restrict__ dst,
                                             const int* __restrict__ t, const int* __restrict__ maxt,
                                             int* __restrict__ win, int E) {
    int j = blockIdx.x * blockDim.x + threadIdx.x;
    if (j < E) {
        int tj = t[j];
        int s = src[j], d = dst[j];
        if (maxt[s] == tj) atomicMax(&win[s], j);
        if (maxt[d] == tj) atomicMax(&win[d], j + E);
    }
}

__global__ __launch_bounds__(256) void k_lu(const int* __restrict__ last_update, const int* __restrict__ maxt,
                                            float* __restrict__ out_lu, int N) {
    int i = blockIdx.x * blockDim.x + threadIdx.x;
    if (i < N) {
        int m = maxt[i], lu = last_update[i];
        out_lu[i] = (float)(m > lu ? m : lu);
    }
}

// ---------------- weight prep: bf16, B-fragment packed, gate-aligned cols + padded K ----------------
// B[((tile*NKS + ks)*64 + lane)*8 + jj] = W^T[k][col], col = (tile/7)*100 + (tile%7)*16 + (lane&15)
__global__ __launch_bounds__(256) void k_prep(const float* __restrict__ w_ih, const float* __restrict__ w_hh,
                                              unsigned short* __restrict__ B) {
    int idx = blockIdx.x * 256 + threadIdx.x;
    if (idx >= BPK_N) return;
    int jj   = idx & 7;
    int lane = (idx >> 3) & 63;
    int rest = idx >> 9;          // tile*NKS + ks
    int ks   = rest % NKS;
    int tile = rest / NKS;
    int gate = tile / 7;
    int tcol = (tile % 7) * 16 + (lane & 15);
    int kk   = ks * 32 + ((lane >> 4) << 3) + jj;
    float v = 0.f;
    if (tcol < 100) {
        int wrow = gate * 100 + tcol;
        if (kk < 512) {
            int col = -1;
            if (kk < 100)                  col = kk;          // mem[node]
            else if (kk >= 104 && kk < 204) col = kk - 4;     // mem[other] -> 100..199
            else if (kk >= 208 && kk < 380) col = kk - 8;     // raw -> 200..371
            else if (kk >= 384 && kk < 484) col = kk - 12;    // tenc -> 372..471
            if (col >= 0) v = w_ih[wrow * WIH_K + col];
        } else {
            int col = kk - 512;
            if (col < 100) v = w_hh[wrow * H + col];
        }
    }
    B[idx] = f2bf(v);
}

// ---------------- fused GRU via bf16 MFMA, in-register gates ----------------
__global__ __launch_bounds__(BLK, 4) void k_gru(
    const int* __restrict__ src, const int* __restrict__ dst, const int* __restrict__ t,
    const float* __restrict__ raw_msg, const float* __restrict__ memory,
    const int* __restrict__ last_update, const float* __restrict__ te_w,
    const float* __restrict__ te_b, const float* __restrict__ b_ih,
    const float* __restrict__ b_hh, const int* __restrict__ win,
    const unsigned short* __restrict__ Bpack,
    float* __restrict__ out_mem, int E, int N)
{
    __shared__ unsigned short sA[GRPS * NKS * SLOTS * 8];   // 62400 B, fragment-ordered
    __shared__ int   s_other[MB];
    __shared__ int   s_j[MB];
    __shared__ int   s_has[MB];
    __shared__ float s_dt[MB];

    const int tid   = threadIdx.x;
    const int node0 = blockIdx.x * MB;

    // --- decode winners ---
    if (tid < MB) {
        int node = node0 + tid;
        int has = 0, j = 0, other = 0; float dt = 0.f;
        if (node < N) {
            int w = win[node];
            if (w >= 0) {
                has = 1;
                int e = (w < E) ? w : (w - E);
                j = e;
                other = (w < E) ? dst[e] : src[e];
                dt = (float)(t[e] - last_update[node]);
            }
        }
        s_j[tid] = j; s_other[tid] = other; s_has[tid] = has; s_dt[tid] = dt;
    }
    __syncthreads();

    // --- stage A: one thread = one 8-col chunk -> one ds_write_b128, fragment layout ---
    for (int item = tid; item < MB * (KTOT / 8); item += BLK) {
        const int n  = item / (KTOT / 8);
        const int c  = item - n * (KTOT / 8);
        const int kb = c * 8;
        const int node = node0 + n;
        float4 va, vb;
        va = make_float4(0.f,0.f,0.f,0.f); vb = va;
        if (kb < 512) {
            if (s_has[n]) {
                if (kb < 104) {
                    va = ld4g(memory + (size_t)node * H, kb, 100);
                    vb = ld4g(memory + (size_t)node * H, kb + 4, 100);
                } else if (kb < 208) {
                    const float* p = memory + (size_t)s_other[n] * H;
                    va = ld4g(p, kb - 104, 100);
                    vb = ld4g(p, kb - 100, 100);
                } else if (kb < 384) {
                    const float* p = raw_msg + (size_t)s_j[n] * RD;
                    va = ld4g(p, kb - 208, RD);
                    vb = ld4g(p, kb - 204, RD);
                } else {
                    const float dt = s_dt[n];
                    const int lc = kb - 384;
                    float vv[8];
#pragma unroll
                    for (int q = 0; q < 8; ++q) {
                        int col = lc + q;
                        vv[q] = (col < 100) ? __cosf(fmaf(dt, te_w[col], te_b[col])) : 0.f;
                    }
                    va = make_float4(vv[0],vv[1],vv[2],vv[3]);
                    vb = make_float4(vv[4],vv[5],vv[6],vv[7]);
                }
            }
        } else {
            if (node < N) {
                const int lc = kb - 512;
                va = ld4g(memory + (size_t)node * H, lc, 100);
                vb = ld4g(memory + (size_t)node * H, lc + 4, 100);
            }
        }
        short8 sv;
        sv[0] = (short)f2bf(va.x); sv[1] = (short)f2bf(va.y);
        sv[2] = (short)f2bf(va.z); sv[3] = (short)f2bf(va.w);
        sv[4] = (short)f2bf(vb.x); sv[5] = (short)f2bf(vb.y);
        sv[6] = (short)f2bf(vb.z); sv[7] = (short)f2bf(vb.w);
        const int ks = c >> 2, sub = c & 3, grp = n >> 4, row = n & 15;
        const int slot = sub * 16 + (row ^ (sub << 2));
        *(short8*)&sA[((grp * NKS + ks) * SLOTS + slot) * 8] = sv;
    }
    __syncthreads();

    // --- MFMA: wave w owns col-slice w*16..w*16+15 of all 3 gates ---
    const int wv    = tid >> 6;          // 0..6
    const int lane  = tid & 63;
    const int lrow  = lane & 15;
    const int lhi   = lane >> 4;
    const int slotl = lhi * 16 + (lrow ^ (lhi << 2));

    f32x4 ai[3][GRPS];     // gate r/z/n, ih(+hh for r,z)
    f32x4 ah2[GRPS];       // n-gate hh part
#pragma unroll
    for (int g = 0; g < 3; ++g)
#pragma unroll
        for (int m = 0; m < GRPS; ++m) ai[g][m] = (f32x4)0.f;
#pragma unroll
    for (int m = 0; m < GRPS; ++m) ah2[m] = (f32x4)0.f;

    for (int ks = 0; ks < KS_IH; ++ks) {
        short8 a0 = *(const short8*)&sA[((0 * NKS + ks) * SLOTS + slotl) * 8];
        short8 a1 = *(const short8*)&sA[((1 * NKS + ks) * SLOTS + slotl) * 8];
        short8 a2 = *(const short8*)&sA[((2 * NKS + ks) * SLOTS + slotl) * 8];
#pragma unroll
        for (int g = 0; g < 3; ++g) {
            const int tile = g * 7 + wv;
            short8 b = *(const short8*)&Bpack[((size_t)(tile * NKS + ks) * 64 + lane) * 8];
            ai[g][0] = mfma16(a0, b, ai[g][0]);
            ai[g][1] = mfma16(a1, b, ai[g][1]);
            ai[g][2] = mfma16(a2, b, ai[g][2]);
        }
    }
    for (int ks = KS_IH; ks < NKS; ++ks) {
        short8 a0 = *(const short8*)&sA[((0 * NKS + ks) * SLOTS + slotl) * 8];
        short8 a1 = *(const short8*)&sA[((1 * NKS + ks) * SLOTS + slotl) * 8];
        short8 a2 = *(const short8*)&sA[((2 * NKS + ks) * SLOTS + slotl) * 8];
        {
            const int tile = 0 * 7 + wv;
            short8 b = *(const short8*)&Bpack[((size_t)(tile * NKS + ks) * 64 + lane) * 8];
            ai[0][0] = mfma16(a0, b, ai[0][0]);
            ai[0][1] = mfma16(a1, b, ai[0][1]);
            ai[0][2] = mfma16(a2, b, ai[0][2]);
        }
        {
            const int tile = 1 * 7 + wv;
            short8 b = *(const short8*)&Bpack[((size_t)(tile * NKS + ks) * 64 + lane) * 8];
            ai[1][0] = mfma16(a0, b, ai[1][0]);
            ai[1][1] = mfma16(a1, b, ai[1][1]);
            ai[1][2] = mfma16(a2, b, ai[1][2]);
        }
        {
            const int tile = 2 * 7 + wv;
            short8 b = *(const short8*)&Bpack[((size_t)(tile * NKS + ks) * 64 + lane) * 8];
            ah2[0] = mfma16(a0, b, ah2[0]);
            ah2[1] = mfma16(a1, b, ah2[1]);
            ah2[2] = mfma16(a2, b, ah2[2]);
        }
    }

    // --- in-register gates + store: lane col c = wv*16 + lrow ---
    const int c = wv * 16 + lrow;
    if (c < 100) {
        const float bir = b_ih[c],       bhr = b_hh[c];
        const float biz = b_ih[c + 100], bhz = b_hh[c + 100];
        const float bin = b_ih[c + 200], bhn = b_hh[c + 200];
#pragma unroll
        for (int m = 0; m < GRPS; ++m) {
#pragma unroll
            for (int r = 0; r < 4; ++r) {
                const int node = node0 + m * 16 + lhi * 4 + r;
                if (node < N) {
                    const float h  = memory[(size_t)node * H + c];
                    const float rg = 1.f / (1.f + __expf(-(ai[0][m][r] + bir + bhr)));
                    const float zg = 1.f / (1.f + __expf(-(ai[1][m][r] + biz + bhz)));
                    const float ng = tanhf(ai[2][m][r] + bin + rg * (ah2[m][r] + bhn));
                    out_mem[(size_t)node * H + c] = (1.f - zg) * ng + zg * h;
                }
            }
        }
    }
}

extern "C" void kernel_launch(void* const* d_in, const int* in_sizes, int n_in,
                              void* d_out, int out_size, void* d_ws, size_t ws_size,
                              hipStream_t stream)
{
    const int*   src         = (const int*)d_in[0];
    const int*   dst         = (const int*)d_in[1];
    const int*   t           = (const int*)d_in[2];
    const float* raw_msg     = (const float*)d_in[3];
    const float* memory      = (const float*)d_in[4];
    const int*   last_update = (const int*)d_in[5];
    const float* te_w        = (const float*)d_in[6];
    const float* te_b        = (const float*)d_in[7];
    const float* w_ih        = (const float*)d_in[8];
    const float* w_hh        = (const float*)d_in[9];
    const float* b_ih        = (const float*)d_in[10];
    const float* b_hh        = (const float*)d_in[11];

    const int E = in_sizes[0];   // 100000
    const int N = in_sizes[5];   // 200000

    float* out    = (float*)d_out;
    float* out_lu = out + (size_t)N * H;

    int* maxt = (int*)d_ws;
    int* win  = maxt + N;
    unsigned short* Bpack = (unsigned short*)(win + N);

    k_init<<<(N + 255) / 256, 256, 0, stream>>>(maxt, win, N);
    k_prep<<<(BPK_N + 255) / 256, 256, 0, stream>>>(w_ih, w_hh, Bpack);
    k_maxt<<<(E + 255) / 256, 256, 0, stream>>>(src, dst, t, maxt, E);
    k_win <<<(E + 255) / 256, 256, 0, stream>>>(src, dst, t, maxt, win, E);
    k_lu  <<<(N + 255) / 256, 256, 0, stream>>>(last_update, maxt, out_lu, N);
    k_gru <<<(N + MB - 1) / MB, BLK, 0, stream>>>(src, dst, t, raw_msg, memory, last_update,
                                                  te_w, te_b, b_ih, b_hh, win, Bpack, out, E, N);
}

// Round 5
// 202.302 us; speedup vs baseline: 18.5245x; 1.7145x over previous
//
#include <hip/hip_runtime.h>
#include <math.h>

typedef __attribute__((ext_vector_type(8))) short  short8;
typedef __attribute__((ext_vector_type(4))) float  f32x4;

// Problem constants: N=200000, E=100000, H=100, R=172, T=100
static constexpr int H     = 100;
static constexpr int RD    = 172;
static constexpr int WK    = 472;            // w_ih K
// Padded K layout (8-col chunks):
//  [0,104)   mem[node]  (msg part, zeroed when no msg)
//  [104,208) mem[other]
//  [208,384) raw_msg (172+4)
//  [384,512) time-enc (100+28)
//  [512,640) mem[node] (hh part, ALWAYS present)
static constexpr int KTOT  = 640;
static constexpr int NKS   = 20;             // K-steps of 32
static constexpr int CH    = 80;             // chunks of 8 per node
static constexpr int MB    = 32;             // nodes per block (200000/32 = 6250 exact)
static constexpr int GRPS  = 2;              // 16-row groups
static constexpr int BLK   = 448;            // 7 waves
static constexpr int SLOTS = 64;             // 16B slots per (grp,ks) tile
// B tiles: [0,7) r-gate (w_hh folded in hh region), [7,14) z-gate (folded),
//          [14,21) n-gate ih (zero in hh region, read only ks<16),
//          [21,28) n-gate hh (read only ks>=16)
static constexpr int NTT   = 28;
static constexpr int BPK_N = NTT * NKS * 64 * 8;   // 286720 bf16

__device__ inline unsigned short f2bf(float x) {
    union { float f; unsigned u; } v; v.f = x;
    return (unsigned short)((v.u + 0x7FFFu + ((v.u >> 16) & 1u)) >> 16);
}
__device__ inline f32x4 mfma16(short8 a, short8 b, f32x4 c) {
    return __builtin_amdgcn_mfma_f32_16x16x32_bf16(a, b, c, 0, 0, 0);
}
__device__ inline float4 ld4g(const float* base, int lc, int limit) {
    if (lc + 4 <= limit) return *(const float4*)(base + lc);
    return make_float4(0.f, 0.f, 0.f, 0.f);
}

// ---------------- aggregation kernels ----------------
__global__ __launch_bounds__(256) void k_init(int* __restrict__ maxt, int* __restrict__ win, int N) {
    int i = blockIdx.x * blockDim.x + threadIdx.x;
    if (i < N) { maxt[i] = (int)0x80000000; win[i] = -1; }
}

__global__ __launch_bounds__(256) void k_maxt(const int* __restrict__ src, const int* __restrict__ dst,
                                              const int* __restrict__ t, int* __restrict__ maxt, int E) {
    int j = blockIdx.x * blockDim.x + threadIdx.x;
    if (j < E) {
        int tj = t[j];
        atomicMax(&maxt[src[j]], tj);
        atomicMax(&maxt[dst[j]], tj);
    }
}

__global__ __launch_bounds__(256) void k_win(const int* __restrict__ src, const int* __restrict__ dst,
                                             const int* __restrict__ t, const int* __restrict__ maxt,
                                             int* __restrict__ win, int E) {
    int j = blockIdx.x * blockDim.x + threadIdx.x;
    if (j < E) {
        int tj = t[j];
        int s = src[j], d = dst[j];
        if (maxt[s] == tj) atomicMax(&win[s], j);
        if (maxt[d] == tj) atomicMax(&win[d], j + E);
    }
}

__global__ __launch_bounds__(256) void k_lu(const int* __restrict__ last_update, const int* __restrict__ maxt,
                                            float* __restrict__ out_lu, int N) {
    int i = blockIdx.x * blockDim.x + threadIdx.x;
    if (i < N) {
        int m = maxt[i], lu = last_update[i];
        out_lu[i] = (float)(m > lu ? m : lu);
    }
}

// ---------------- weight prep ----------------
__global__ __launch_bounds__(256) void k_prep(const float* __restrict__ w_ih, const float* __restrict__ w_hh,
                                              unsigned short* __restrict__ B) {
    int idx = blockIdx.x * 256 + threadIdx.x;
    if (idx >= BPK_N) return;
    int jj   = idx & 7;
    int lane = (idx >> 3) & 63;
    int rest = idx >> 9;          // tile*NKS + ks
    int ks   = rest % NKS;
    int tile = rest / NKS;
    int kk   = ks * 32 + ((lane >> 4) << 3) + jj;
    float v = 0.f;
    if (tile < 21) {
        int gate = tile / 7;
        int tcol = (tile % 7) * 16 + (lane & 15);
        if (tcol < 100) {
            if (kk < 512) {
                int col = -1;
                if (kk < 100)                   col = kk;          // mem[node]
                else if (kk >= 104 && kk < 204) col = kk - 4;      // mem[other]
                else if (kk >= 208 && kk < 380) col = kk - 8;      // raw
                else if (kk >= 384 && kk < 484) col = kk - 12;     // tenc
                if (col >= 0) v = w_ih[(gate * 100 + tcol) * WK + col];
            } else {
                int khh = kk - 512;
                if (gate < 2 && khh < 100)                          // fold w_hh for r,z
                    v = w_hh[(gate * 100 + tcol) * H + khh];
            }
        }
    } else {
        int tcol = (tile - 21) * 16 + (lane & 15);
        int khh  = kk - 512;
        if (tcol < 100 && khh >= 0 && khh < 100)
            v = w_hh[(200 + tcol) * H + khh];
    }
    B[idx] = f2bf(v);
}

// ---------------- fused GRU via bf16 MFMA ----------------
__global__ __launch_bounds__(BLK, 6) void k_gru(
    const int* __restrict__ src, const int* __restrict__ dst, const int* __restrict__ t,
    const float* __restrict__ raw_msg, const float* __restrict__ memory,
    const int* __restrict__ last_update, const float* __restrict__ te_w,
    const float* __restrict__ te_b, const float* __restrict__ b_ih,
    const float* __restrict__ b_hh, const int* __restrict__ win,
    const unsigned short* __restrict__ Bpack,
    float* __restrict__ out_mem, int E, int N)
{
    __shared__ unsigned short sA[GRPS * NKS * SLOTS * 8];   // 40960 B
    __shared__ int   s_other[MB];
    __shared__ int   s_j[MB];
    __shared__ int   s_has[MB];
    __shared__ float s_dt[MB];

    const int tid   = threadIdx.x;
    const int node0 = blockIdx.x * MB;

    // --- decode winners ---
    if (tid < MB) {
        int node = node0 + tid;
        int w = win[node];
        int has = 0, j = 0, other = 0; float dt = 0.f;
        if (w >= 0) {
            has = 1;
            int e = (w < E) ? w : (w - E);
            j = e;
            other = (w < E) ? dst[e] : src[e];
            dt = (float)(t[e] - last_update[node]);
        }
        s_j[tid] = j; s_other[tid] = other; s_has[tid] = has; s_dt[tid] = dt;
    }
    __syncthreads();

    // --- stage A, c-major: thread's node nl = tid&31 is FIXED; c walks by 14 ---
    {
        const int nl    = tid & 31;
        const int node  = node0 + nl;
        const int has   = s_has[nl];
        const int other = s_other[nl];
        const int jw    = s_j[nl];
        const float dt  = s_dt[nl];
        const float* memN = memory + (size_t)node * H;
        const float* memO = memory + (size_t)other * H;
        const float* rawJ = raw_msg + (size_t)jw * RD;
        const int grp = nl >> 4;
        const int row = nl & 15;

        for (int c = tid >> 5; c < CH; c += BLK / 32) {
            const int kb = c * 8;
            float4 va = make_float4(0.f, 0.f, 0.f, 0.f), vb = va;
            if (kb < 512) {
                if (has) {
                    if (kb < 104)      { va = ld4g(memN, kb,       100); vb = ld4g(memN, kb + 4,   100); }
                    else if (kb < 208) { va = ld4g(memO, kb - 104, 100); vb = ld4g(memO, kb - 100, 100); }
                    else if (kb < 384) { va = ld4g(rawJ, kb - 208, RD ); vb = ld4g(rawJ, kb - 204, RD ); }
                    else {
                        const int lc = kb - 384;
                        float vv[8];
#pragma unroll
                        for (int q = 0; q < 8; ++q) {
                            int col = lc + q;
                            vv[q] = (col < 100) ? __cosf(fmaf(dt, te_w[col], te_b[col])) : 0.f;
                        }
                        va = make_float4(vv[0], vv[1], vv[2], vv[3]);
                        vb = make_float4(vv[4], vv[5], vv[6], vv[7]);
                    }
                }
            } else {
                va = ld4g(memN, kb - 512, 100);
                vb = ld4g(memN, kb - 508, 100);
            }
            short8 sv;
            sv[0] = (short)f2bf(va.x); sv[1] = (short)f2bf(va.y);
            sv[2] = (short)f2bf(va.z); sv[3] = (short)f2bf(va.w);
            sv[4] = (short)f2bf(vb.x); sv[5] = (short)f2bf(vb.y);
            sv[6] = (short)f2bf(vb.z); sv[7] = (short)f2bf(vb.w);
            const int ks  = c >> 2, sub = c & 3;
            const int slot = sub * 16 + (row ^ (sub << 2));
            *(short8*)&sA[((grp * NKS + ks) * SLOTS + slot) * 8] = sv;
        }
    }
    __syncthreads();

    // --- MFMA: wave wv owns output cols wv*16..wv*16+15 of all 3 gates ---
    const int wv    = tid >> 6;          // 0..6
    const int lane  = tid & 63;
    const int lrow  = lane & 15;
    const int lhi   = lane >> 4;
    const int slotl = lhi * 16 + (lrow ^ (lhi << 2));

    f32x4 ar[GRPS], az[GRPS], an[GRPS], ah[GRPS];
#pragma unroll
    for (int m = 0; m < GRPS; ++m) { ar[m] = (f32x4)0.f; az[m] = (f32x4)0.f; an[m] = (f32x4)0.f; ah[m] = (f32x4)0.f; }

    __builtin_amdgcn_s_setprio(1);
#pragma unroll
    for (int ks = 0; ks < NKS; ++ks) {
        short8 a0 = *(const short8*)&sA[((0 * NKS + ks) * SLOTS + slotl) * 8];
        short8 a1 = *(const short8*)&sA[((1 * NKS + ks) * SLOTS + slotl) * 8];
        short8 br = *(const short8*)&Bpack[(((size_t)(     wv) * NKS + ks) * 64 + lane) * 8];
        short8 bz = *(const short8*)&Bpack[(((size_t)( 7 + wv) * NKS + ks) * 64 + lane) * 8];
        short8 bn = (ks < 16)
                  ? *(const short8*)&Bpack[(((size_t)(14 + wv) * NKS + ks) * 64 + lane) * 8]
                  : *(const short8*)&Bpack[(((size_t)(21 + wv) * NKS + ks) * 64 + lane) * 8];
        ar[0] = mfma16(a0, br, ar[0]);  ar[1] = mfma16(a1, br, ar[1]);
        az[0] = mfma16(a0, bz, az[0]);  az[1] = mfma16(a1, bz, az[1]);
        if (ks < 16) { an[0] = mfma16(a0, bn, an[0]);  an[1] = mfma16(a1, bn, an[1]); }
        else         { ah[0] = mfma16(a0, bn, ah[0]);  ah[1] = mfma16(a1, bn, ah[1]); }
    }
    __builtin_amdgcn_s_setprio(0);

    // --- in-register gates + store ---
    const int c = wv * 16 + lrow;
    if (c < 100) {
        const float br_ = b_ih[c]       + b_hh[c];
        const float bz_ = b_ih[c + 100] + b_hh[c + 100];
        const float bin = b_ih[c + 200];
        const float bhn = b_hh[c + 200];
#pragma unroll
        for (int m = 0; m < GRPS; ++m) {
#pragma unroll
            for (int r = 0; r < 4; ++r) {
                const int node = node0 + m * 16 + lhi * 4 + r;
                const float h  = memory[(size_t)node * H + c];
                const float rg = 1.f / (1.f + __expf(-(ar[m][r] + br_)));
                const float zg = 1.f / (1.f + __expf(-(az[m][r] + bz_)));
                const float ng = tanhf(an[m][r] + bin + rg * (ah[m][r] + bhn));
                out_mem[(size_t)node * H + c] = (1.f - zg) * ng + zg * h;
            }
        }
    }
}

extern "C" void kernel_launch(void* const* d_in, const int* in_sizes, int n_in,
                              void* d_out, int out_size, void* d_ws, size_t ws_size,
                              hipStream_t stream)
{
    const int*   src         = (const int*)d_in[0];
    const int*   dst         = (const int*)d_in[1];
    const int*   t           = (const int*)d_in[2];
    const float* raw_msg     = (const float*)d_in[3];
    const float* memory      = (const float*)d_in[4];
    const int*   last_update = (const int*)d_in[5];
    const float* te_w        = (const float*)d_in[6];
    const float* te_b        = (const float*)d_in[7];
    const float* w_ih        = (const float*)d_in[8];
    const float* w_hh        = (const float*)d_in[9];
    const float* b_ih        = (const float*)d_in[10];
    const float* b_hh        = (const float*)d_in[11];

    const int E = in_sizes[0];   // 100000
    const int N = in_sizes[5];   // 200000

    float* out    = (float*)d_out;
    float* out_lu = out + (size_t)N * H;

    int* maxt = (int*)d_ws;
    int* win  = maxt + N;
    unsigned short* Bpack = (unsigned short*)(win + N);

    k_init<<<(N + 255) / 256, 256, 0, stream>>>(maxt, win, N);
    k_prep<<<(BPK_N + 255) / 256, 256, 0, stream>>>(w_ih, w_hh, Bpack);
    k_maxt<<<(E + 255) / 256, 256, 0, stream>>>(src, dst, t, maxt, E);
    k_win <<<(E + 255) / 256, 256, 0, stream>>>(src, dst, t, maxt, win, E);
    k_lu  <<<(N + 255) / 256, 256, 0, stream>>>(last_update, maxt, out_lu, N);
    k_gru <<<N / MB, BLK, 0, stream>>>(src, dst, t, raw_msg, memory, last_update,
                                       te_w, te_b, b_ih, b_hh, win, Bpack, out, E, N);
}